// Round 6
// baseline (254.429 us; speedup 1.0000x reference)
//
#include <hip/hip_runtime.h>
#include <math.h>

#define NN 50000
#define NE 800000
#define IN_F 256
#define HF 256   // H*F
#define NH 8
#define NEG_SLOPE 0.2f

#define DEG_PAD 57344   // 7 * 8192, scan processes 8192/iter unguarded

typedef short bf16x8 __attribute__((ext_vector_type(8)));
typedef float f32x16 __attribute__((ext_vector_type(16)));

__device__ __forceinline__ unsigned short f2bf(float x) {
    unsigned u = __float_as_uint(x);
    u += 0x7FFF + ((u >> 16) & 1);          // round-to-nearest-even
    return (unsigned short)(u >> 16);
}
__device__ __forceinline__ float bf2f(unsigned short b) {
    return __uint_as_float(((unsigned)b) << 16);
}

// ---- fused: W -> swizzled bf16, and degree count ---------------------------
__global__ void wdeg_kernel(const float* __restrict__ W,
                            unsigned short* __restrict__ Wb_hi,
                            const int* __restrict__ dst, int* __restrict__ deg) {
    int e = blockIdx.x * 256 + threadIdx.x;
    if (e < NE) atomicAdd(&deg[dst[e]], 1);
    if (e < IN_F * HF) {
        int k = e >> 8, n = e & 255;
        float x = W[e];
        int kt = k >> 5, kk = k & 31, c = kk >> 3, j = kk & 7;
        int slot = c ^ (n & 3);
        Wb_hi[((size_t)(kt * 256 + n)) * 32 + slot * 8 + j] = f2bf(x);
    }
}

// ---- GEMM: h_bf16 = bf16(feat @ W), 2-term bf16-split MFMA -----------------
__global__ __launch_bounds__(256) void gemm_kernel(const float* __restrict__ feat,
                                                   const unsigned short* __restrict__ Wb_hi,
                                                   unsigned short* __restrict__ h, int M) {
    __shared__ __align__(16) unsigned short As_hi[64][32];
    __shared__ __align__(16) unsigned short As_lo[64][32];
    __shared__ __align__(16) unsigned short Bs_hi[256][32];

    const int tid = threadIdx.x;
    const int lane = tid & 63;
    const int wid = tid >> 6;
    const int bm = blockIdx.x * 64;

    f32x16 acc[2][2];
    #pragma unroll
    for (int mi = 0; mi < 2; ++mi)
        #pragma unroll
        for (int ni = 0; ni < 2; ++ni)
            #pragma unroll
            for (int r = 0; r < 16; ++r) acc[mi][ni][r] = 0.f;

    const int arow = tid >> 2;
    const int achk = tid & 3;
    const int aslot = achk ^ (arow & 3);
    const int grow = bm + arow;
    const float* aptr = feat + (size_t)grow * IN_F + achk * 8;

    for (int kt = 0; kt < 8; ++kt) {
        __syncthreads();
        float4 f0 = make_float4(0.f, 0.f, 0.f, 0.f), f1 = f0;
        if (grow < M) {
            f0 = *(const float4*)(aptr + kt * 32);
            f1 = *(const float4*)(aptr + kt * 32 + 4);
        }
        float xs[8] = {f0.x, f0.y, f0.z, f0.w, f1.x, f1.y, f1.z, f1.w};
        unsigned hi2[4], lo2[4];
        #pragma unroll
        for (int p = 0; p < 4; ++p) {
            unsigned short h0 = f2bf(xs[2 * p]), h1 = f2bf(xs[2 * p + 1]);
            unsigned short l0 = f2bf(xs[2 * p] - bf2f(h0));
            unsigned short l1 = f2bf(xs[2 * p + 1] - bf2f(h1));
            hi2[p] = (unsigned)h0 | ((unsigned)h1 << 16);
            lo2[p] = (unsigned)l0 | ((unsigned)l1 << 16);
        }
        *(int4*)&As_hi[arow][aslot * 8] = make_int4(hi2[0], hi2[1], hi2[2], hi2[3]);
        *(int4*)&As_lo[arow][aslot * 8] = make_int4(lo2[0], lo2[1], lo2[2], lo2[3]);
        {
            const int4* gh = (const int4*)(Wb_hi + (size_t)kt * 8192) + tid * 4;
            int4* dh = (int4*)&Bs_hi[tid][0];
            #pragma unroll
            for (int q = 0; q < 4; ++q) dh[q] = gh[q];
        }
        __syncthreads();
        #pragma unroll
        for (int ksc = 0; ksc < 2; ++ksc) {
            bf16x8 ah[2], av[2], bh[2];
            const int kc = ksc * 2 + (lane >> 5);
            #pragma unroll
            for (int mi = 0; mi < 2; ++mi) {
                int r = mi * 32 + (lane & 31);
                int slot = kc ^ (r & 3);
                ah[mi] = *(const bf16x8*)&As_hi[r][slot * 8];
                av[mi] = *(const bf16x8*)&As_lo[r][slot * 8];
            }
            #pragma unroll
            for (int ni = 0; ni < 2; ++ni) {
                int n = wid * 64 + ni * 32 + (lane & 31);
                int slot = kc ^ (n & 3);
                bh[ni] = *(const bf16x8*)&Bs_hi[n][slot * 8];
            }
            #pragma unroll
            for (int mi = 0; mi < 2; ++mi)
                #pragma unroll
                for (int ni = 0; ni < 2; ++ni) {
                    acc[mi][ni] = __builtin_amdgcn_mfma_f32_32x32x16_bf16(ah[mi], bh[ni], acc[mi][ni], 0, 0, 0);
                    acc[mi][ni] = __builtin_amdgcn_mfma_f32_32x32x16_bf16(av[mi], bh[ni], acc[mi][ni], 0, 0, 0);
                }
        }
    }
    #pragma unroll
    for (int mi = 0; mi < 2; ++mi)
        #pragma unroll
        for (int ni = 0; ni < 2; ++ni)
            #pragma unroll
            for (int r = 0; r < 16; ++r) {
                int row = mi * 32 + (r & 3) + 8 * (r >> 2) + 4 * (lane >> 5);
                int col = wid * 64 + ni * 32 + (lane & 31);
                int gr = bm + row;
                if (gr < M) h[(size_t)gr * HF + col] = f2bf(acc[mi][ni][r]);
            }
}

// ---- el/er per node --------------------------------------------------------
__global__ __launch_bounds__(256) void elr_kernel(const unsigned short* __restrict__ h,
                                                  const float* __restrict__ al,
                                                  const float* __restrict__ ar,
                                                  float* __restrict__ el,
                                                  float* __restrict__ er) {
    int node = blockIdx.x * 4 + (threadIdx.x >> 6);
    if (node >= NN) return;
    int lane = threadIdx.x & 63;
    short4 hv = *(const short4*)&h[(size_t)node * HF + lane * 4];
    float h0 = bf2f((unsigned short)hv.x), h1 = bf2f((unsigned short)hv.y);
    float h2 = bf2f((unsigned short)hv.z), h3 = bf2f((unsigned short)hv.w);
    float4 alv = *(const float4*)&al[lane * 4];
    float4 arv = *(const float4*)&ar[lane * 4];
    float pl = h0 * alv.x + h1 * alv.y + h2 * alv.z + h3 * alv.w;
    float pr = h0 * arv.x + h1 * arv.y + h2 * arv.z + h3 * arv.w;
    #pragma unroll
    for (int off = 1; off < 8; off <<= 1) {
        pl += __shfl_xor(pl, off);
        pr += __shfl_xor(pr, off);
    }
    if ((lane & 7) == 0) {
        el[node * NH + (lane >> 3)] = pl;
        er[node * NH + (lane >> 3)] = pr;
    }
}

// ---- CSR build -------------------------------------------------------------
__global__ __launch_bounds__(1024) void scan_kernel(const int* __restrict__ deg,
                                                    int* __restrict__ row_ptr,
                                                    int* __restrict__ cursor) {
    __shared__ int wsum[16];
    int tid = threadIdx.x, lane = tid & 63, wid = tid >> 6;
    int carry = 0;
    if (tid == 0) row_ptr[0] = 0;
    for (int base = 0; base < DEG_PAD; base += 8192) {
        int i0 = base + tid * 8;
        int4 a = *(const int4*)&deg[i0];
        int4 b = *(const int4*)&deg[i0 + 4];
        int v[8] = {a.x, a.y, a.z, a.w, b.x, b.y, b.z, b.w};
        int s8 = 0;
        #pragma unroll
        for (int j = 0; j < 8; ++j) s8 += v[j];
        int x = s8;
        #pragma unroll
        for (int off = 1; off < 64; off <<= 1) {
            int y = __shfl_up(x, off);
            if (lane >= off) x += y;
        }
        if (lane == 63) wsum[wid] = x;
        __syncthreads();
        int wadd = 0, tot = 0;
        #pragma unroll
        for (int w = 0; w < 16; ++w) {
            int s = wsum[w];
            tot += s;
            if (w < wid) wadd += s;
        }
        int r = carry + wadd + (x - s8);
        #pragma unroll
        for (int j = 0; j < 8; ++j) {
            int i = i0 + j;
            if (i < NN) { cursor[i] = r; row_ptr[i + 1] = r + v[j]; }
            r += v[j];
        }
        carry += tot;
        __syncthreads();
    }
}

__global__ void fill_kernel(const int* __restrict__ src, const int* __restrict__ dst,
                            int* __restrict__ cursor, int* __restrict__ csr_src) {
    int e = blockIdx.x * 256 + threadIdx.x;
    if (e < NE) {
        int pos = atomicAdd(&cursor[dst[e]], 1);
        csr_src[pos] = src[e];
    }
}

// ---- single-pass aggregate: lane = feature chunk (4 floats), 8 edges/iter --
__global__ __launch_bounds__(256) void agg_kernel(const unsigned short* __restrict__ h,
                                                  const float* __restrict__ el,
                                                  const float* __restrict__ er,
                                                  const int* __restrict__ row_ptr,
                                                  const int* __restrict__ csr_src,
                                                  const float* __restrict__ bias,
                                                  float* __restrict__ out) {
    int node = blockIdx.x * 4 + (threadIdx.x >> 6);
    if (node >= NN) return;
    int lane = threadIdx.x & 63;
    int hd = lane >> 3;                 // head of features [lane*4, lane*4+4)
    int beg = row_ptr[node];
    int end = row_ptr[node + 1];
    float er_mine = er[(size_t)node * NH + hd];

    float ssum = 0.f;
    float4 acc = make_float4(0.f, 0.f, 0.f, 0.f);

    for (int i0 = beg; i0 < end; i0 += 8) {
        int s[8]; float p[8];
        #pragma unroll
        for (int j = 0; j < 8; ++j) {
            int idx = i0 + j;
            bool v = idx < end;
            s[j] = csr_src[v ? idx : beg];
            float e = el[(size_t)s[j] * NH + hd] + er_mine;
            e = e > 0.f ? e : NEG_SLOPE * e;
            p[j] = v ? __expf(e) : 0.f;
        }
        #pragma unroll
        for (int j = 0; j < 8; ++j) {
            short4 hv = *(const short4*)&h[(size_t)s[j] * HF + lane * 4];
            ssum += p[j];
            acc.x = fmaf(bf2f((unsigned short)hv.x), p[j], acc.x);
            acc.y = fmaf(bf2f((unsigned short)hv.y), p[j], acc.y);
            acc.z = fmaf(bf2f((unsigned short)hv.z), p[j], acc.z);
            acc.w = fmaf(bf2f((unsigned short)hv.w), p[j], acc.w);
        }
    }

    float inv_s = (ssum > 0.f) ? 1.f / ssum : 0.f;
    int col = lane * 4;
    float4 bv = *(const float4*)&bias[col];
    float4 o = make_float4(fmaf(acc.x, inv_s, bv.x), fmaf(acc.y, inv_s, bv.y),
                           fmaf(acc.z, inv_s, bv.z), fmaf(acc.w, inv_s, bv.w));
    *(float4*)&out[(size_t)node * HF + col] = o;
}

extern "C" void kernel_launch(void* const* d_in, const int* in_sizes, int n_in,
                              void* d_out, int out_size, void* d_ws, size_t ws_size,
                              hipStream_t stream) {
    const float* feat = (const float*)d_in[0];
    const float* W    = (const float*)d_in[1];
    const float* al   = (const float*)d_in[2];
    const float* ar   = (const float*)d_in[3];
    const float* bias = (const float*)d_in[4];
    const int*   src  = (const int*)d_in[5];
    const int*   dst  = (const int*)d_in[6];
    float* out = (float*)d_out;

    char* ws = (char*)d_ws;
    size_t off = 0;
    unsigned short* h = (unsigned short*)(ws + off); off += (size_t)NN * HF * 2;     // 25.6 MB
    float* el = (float*)(ws + off);                  off += (size_t)NN * NH * 4;
    float* er = (float*)(ws + off);                  off += (size_t)NN * NH * 4;
    int* deg = (int*)(ws + off);                     off += (size_t)DEG_PAD * 4;
    int* row_ptr = (int*)(ws + off);                 off += (size_t)(NN + 1) * 4 + 60;
    off &= ~(size_t)63;
    int* cursor = (int*)(ws + off);                  off += (size_t)NN * 4;
    int* csr_src = (int*)(ws + off);                 off += (size_t)NE * 4;
    unsigned short* Wb_hi = (unsigned short*)(ws + off); off += (size_t)IN_F * HF * 2;

    hipMemsetAsync(deg, 0, (size_t)DEG_PAD * 4, stream);

    wdeg_kernel<<<NE / 256, 256, 0, stream>>>(W, Wb_hi, dst, deg);
    gemm_kernel<<<(NN + 63) / 64, 256, 0, stream>>>(feat, Wb_hi, h, NN);
    elr_kernel<<<NN / 4, 256, 0, stream>>>(h, al, ar, el, er);
    scan_kernel<<<1, 1024, 0, stream>>>(deg, row_ptr, cursor);
    fill_kernel<<<NE / 256, 256, 0, stream>>>(src, dst, cursor, csr_src);
    agg_kernel<<<(NN + 3) / 4, 256, 0, stream>>>(h, el, er, row_ptr, csr_src, bias, out);
}

// Round 7
// 249.167 us; speedup vs baseline: 1.0211x; 1.0211x over previous
//
#include <hip/hip_runtime.h>
#include <math.h>

#define NN 50000
#define NE 800000
#define IN_F 256
#define HF 256   // H*F
#define NH 8
#define NEG_SLOPE 0.2f

#define DEG_PAD 51200   // 25 * 2048, scan processes 2048/iter unguarded

#define GEMM_BLOCKS 782   // ceil(50000/64)
#define EDGE_BLOCKS 3125  // 800000/256

typedef short bf16x8 __attribute__((ext_vector_type(8)));
typedef float f32x16 __attribute__((ext_vector_type(16)));

__device__ __forceinline__ unsigned short f2bf(float x) {
    unsigned u = __float_as_uint(x);
    u += 0x7FFF + ((u >> 16) & 1);          // round-to-nearest-even
    return (unsigned short)(u >> 16);
}
__device__ __forceinline__ float bf2f(unsigned short b) {
    return __uint_as_float(((unsigned)b) << 16);
}

// ---- K0: W -> swizzled bf16 (blocks 0..255) + deg zero (blocks 256..) ------
__global__ __launch_bounds__(256) void k0_setup(const float* __restrict__ W,
                                                unsigned short* __restrict__ Wb_hi,
                                                int* __restrict__ deg) {
    int bid = blockIdx.x;
    if (bid < 256) {
        int e = bid * 256 + threadIdx.x;   // 65536 = 256k x 256n
        int k = e >> 8, n = e & 255;
        float x = W[e];
        int kt = k >> 5, kk = k & 31, c = kk >> 3, j = kk & 7;
        int slot = c ^ (n & 3);
        Wb_hi[((size_t)(kt * 256 + n)) * 32 + slot * 8 + j] = f2bf(x);
    } else {
        int i = (bid - 256) * 256 + threadIdx.x;
        if (i < DEG_PAD) deg[i] = 0;
    }
}

// ---- K1: gemm (blocks 0..781) || degree count (blocks 782..3906) -----------
// gemm: h_bf16 = bf16(feat @ W), 2-term bf16-split MFMA (a_hi+a_lo)*b_hi
__global__ __launch_bounds__(256) void k1_gemm_deg(const float* __restrict__ feat,
                                                   const unsigned short* __restrict__ Wb_hi,
                                                   unsigned short* __restrict__ h,
                                                   const int* __restrict__ dst,
                                                   int* __restrict__ deg, int M) {
    __shared__ __align__(16) unsigned short As_hi[64][32];
    __shared__ __align__(16) unsigned short As_lo[64][32];
    __shared__ __align__(16) unsigned short Bs_hi[256][32];

    const int bid = blockIdx.x;
    if (bid >= GEMM_BLOCKS) {
        int e = (bid - GEMM_BLOCKS) * 256 + threadIdx.x;
        if (e < NE) atomicAdd(&deg[dst[e]], 1);
        return;
    }

    const int tid = threadIdx.x;
    const int lane = tid & 63;
    const int wid = tid >> 6;
    const int bm = bid * 64;

    f32x16 acc[2][2];
    #pragma unroll
    for (int mi = 0; mi < 2; ++mi)
        #pragma unroll
        for (int ni = 0; ni < 2; ++ni)
            #pragma unroll
            for (int r = 0; r < 16; ++r) acc[mi][ni][r] = 0.f;

    const int arow = tid >> 2;
    const int achk = tid & 3;
    const int aslot = achk ^ (arow & 3);
    const int grow = bm + arow;
    const float* aptr = feat + (size_t)grow * IN_F + achk * 8;

    for (int kt = 0; kt < 8; ++kt) {
        __syncthreads();
        float4 f0 = make_float4(0.f, 0.f, 0.f, 0.f), f1 = f0;
        if (grow < M) {
            f0 = *(const float4*)(aptr + kt * 32);
            f1 = *(const float4*)(aptr + kt * 32 + 4);
        }
        float xs[8] = {f0.x, f0.y, f0.z, f0.w, f1.x, f1.y, f1.z, f1.w};
        unsigned hi2[4], lo2[4];
        #pragma unroll
        for (int p = 0; p < 4; ++p) {
            unsigned short h0 = f2bf(xs[2 * p]), h1 = f2bf(xs[2 * p + 1]);
            unsigned short l0 = f2bf(xs[2 * p] - bf2f(h0));
            unsigned short l1 = f2bf(xs[2 * p + 1] - bf2f(h1));
            hi2[p] = (unsigned)h0 | ((unsigned)h1 << 16);
            lo2[p] = (unsigned)l0 | ((unsigned)l1 << 16);
        }
        *(int4*)&As_hi[arow][aslot * 8] = make_int4(hi2[0], hi2[1], hi2[2], hi2[3]);
        *(int4*)&As_lo[arow][aslot * 8] = make_int4(lo2[0], lo2[1], lo2[2], lo2[3]);
        {
            const int4* gh = (const int4*)(Wb_hi + (size_t)kt * 8192) + tid * 4;
            int4* dh = (int4*)&Bs_hi[tid][0];
            #pragma unroll
            for (int q = 0; q < 4; ++q) dh[q] = gh[q];
        }
        __syncthreads();
        #pragma unroll
        for (int ksc = 0; ksc < 2; ++ksc) {
            bf16x8 ah[2], av[2], bh[2];
            const int kc = ksc * 2 + (lane >> 5);
            #pragma unroll
            for (int mi = 0; mi < 2; ++mi) {
                int r = mi * 32 + (lane & 31);
                int slot = kc ^ (r & 3);
                ah[mi] = *(const bf16x8*)&As_hi[r][slot * 8];
                av[mi] = *(const bf16x8*)&As_lo[r][slot * 8];
            }
            #pragma unroll
            for (int ni = 0; ni < 2; ++ni) {
                int n = wid * 64 + ni * 32 + (lane & 31);
                int slot = kc ^ (n & 3);
                bh[ni] = *(const bf16x8*)&Bs_hi[n][slot * 8];
            }
            #pragma unroll
            for (int mi = 0; mi < 2; ++mi)
                #pragma unroll
                for (int ni = 0; ni < 2; ++ni) {
                    acc[mi][ni] = __builtin_amdgcn_mfma_f32_32x32x16_bf16(ah[mi], bh[ni], acc[mi][ni], 0, 0, 0);
                    acc[mi][ni] = __builtin_amdgcn_mfma_f32_32x32x16_bf16(av[mi], bh[ni], acc[mi][ni], 0, 0, 0);
                }
        }
    }
    #pragma unroll
    for (int mi = 0; mi < 2; ++mi)
        #pragma unroll
        for (int ni = 0; ni < 2; ++ni)
            #pragma unroll
            for (int r = 0; r < 16; ++r) {
                int row = mi * 32 + (r & 3) + 8 * (r >> 2) + 4 * (lane >> 5);
                int col = wid * 64 + ni * 32 + (lane & 31);
                int gr = bm + row;
                if (gr < M) h[(size_t)gr * HF + col] = f2bf(acc[mi][ni][r]);
            }
}

// ---- K2: elr (blocks 0..12499) || scan (block 12500, 256 thr, 8/thread) ----
__global__ __launch_bounds__(256) void k2_elr_scan(const unsigned short* __restrict__ h,
                                                   const float* __restrict__ al,
                                                   const float* __restrict__ ar,
                                                   float* __restrict__ el,
                                                   float* __restrict__ er,
                                                   const int* __restrict__ deg,
                                                   int* __restrict__ row_ptr,
                                                   int* __restrict__ cursor) {
    __shared__ int wsum[4];
    int bid = blockIdx.x;
    if (bid < 12500) {
        int node = bid * 4 + (threadIdx.x >> 6);
        if (node >= NN) return;
        int lane = threadIdx.x & 63;
        short4 hv = *(const short4*)&h[(size_t)node * HF + lane * 4];
        float h0 = bf2f((unsigned short)hv.x), h1 = bf2f((unsigned short)hv.y);
        float h2 = bf2f((unsigned short)hv.z), h3 = bf2f((unsigned short)hv.w);
        float4 alv = *(const float4*)&al[lane * 4];
        float4 arv = *(const float4*)&ar[lane * 4];
        float pl = h0 * alv.x + h1 * alv.y + h2 * alv.z + h3 * alv.w;
        float pr = h0 * arv.x + h1 * arv.y + h2 * arv.z + h3 * arv.w;
        #pragma unroll
        for (int off = 1; off < 8; off <<= 1) {
            pl += __shfl_xor(pl, off);
            pr += __shfl_xor(pr, off);
        }
        if ((lane & 7) == 0) {
            el[node * NH + (lane >> 3)] = pl;
            er[node * NH + (lane >> 3)] = pr;
        }
        return;
    }
    // ---- scan: single block, 256 threads, 8 elements/thread, 25 iters ----
    int tid = threadIdx.x, lane = tid & 63, wid = tid >> 6;
    int carry = 0;
    if (tid == 0) row_ptr[0] = 0;
    for (int base = 0; base < DEG_PAD; base += 2048) {
        int i0 = base + tid * 8;
        int4 a = *(const int4*)&deg[i0];
        int4 b = *(const int4*)&deg[i0 + 4];
        int v[8] = {a.x, a.y, a.z, a.w, b.x, b.y, b.z, b.w};
        int s8 = 0;
        #pragma unroll
        for (int j = 0; j < 8; ++j) s8 += v[j];
        int x = s8;
        #pragma unroll
        for (int off = 1; off < 64; off <<= 1) {
            int y = __shfl_up(x, off);
            if (lane >= off) x += y;
        }
        if (lane == 63) wsum[wid] = x;
        __syncthreads();
        int wadd = 0, tot = 0;
        #pragma unroll
        for (int w = 0; w < 4; ++w) {
            int s = wsum[w];
            tot += s;
            if (w < wid) wadd += s;
        }
        int r = carry + wadd + (x - s8);
        #pragma unroll
        for (int j = 0; j < 8; ++j) {
            int i = i0 + j;
            if (i < NN) { cursor[i] = r; row_ptr[i + 1] = r + v[j]; }
            r += v[j];
        }
        carry += tot;
        __syncthreads();
    }
}

// ---- K3: fill CSR ----------------------------------------------------------
__global__ void fill_kernel(const int* __restrict__ src, const int* __restrict__ dst,
                            int* __restrict__ cursor, int* __restrict__ csr_src) {
    int e = blockIdx.x * 256 + threadIdx.x;
    if (e < NE) {
        int pos = atomicAdd(&cursor[dst[e]], 1);
        csr_src[pos] = src[e];
    }
}

// ---- K4: single-pass aggregate: lane = edge_slot(3b) x head(3b), 16/iter ---
__global__ __launch_bounds__(256) void agg_kernel(const unsigned short* __restrict__ h,
                                                  const float* __restrict__ el,
                                                  const float* __restrict__ er,
                                                  const int* __restrict__ row_ptr,
                                                  const int* __restrict__ csr_src,
                                                  const float* __restrict__ bias,
                                                  float* __restrict__ out) {
    int node = blockIdx.x * 4 + (threadIdx.x >> 6);
    if (node >= NN) return;
    int lane = threadIdx.x & 63;
    int eg = lane >> 3;        // edge slot
    int fg = lane & 7;         // head (32 features)
    int beg = row_ptr[node];
    int end = row_ptr[node + 1];
    float er_mine = er[(size_t)node * NH + fg];

    float ssum = 0.f;
    float acc[32];
    #pragma unroll
    for (int j = 0; j < 32; ++j) acc[j] = 0.f;

    for (int i0 = beg; i0 < end; i0 += 16) {
        int idxA = i0 + eg;
        int idxB = i0 + 8 + eg;
        bool vA = idxA < end, vB = idxB < end;
        int sA = csr_src[vA ? idxA : beg];
        int sB = csr_src[vB ? idxB : beg];
        float eA = el[(size_t)sA * NH + fg] + er_mine;
        float eB = el[(size_t)sB * NH + fg] + er_mine;
        eA = eA > 0.f ? eA : NEG_SLOPE * eA;
        eB = eB > 0.f ? eB : NEG_SLOPE * eB;
        float pA = vA ? __expf(eA) : 0.f;
        float pB = vB ? __expf(eB) : 0.f;
        ssum += pA + pB;
        const unsigned short* hpA = h + (size_t)sA * HF + fg * 32;
        const unsigned short* hpB = h + (size_t)sB * HF + fg * 32;
        bf16x8 va[4], vb[4];
        #pragma unroll
        for (int c = 0; c < 4; ++c) { va[c] = *(const bf16x8*)(hpA + c * 8); }
        #pragma unroll
        for (int c = 0; c < 4; ++c) { vb[c] = *(const bf16x8*)(hpB + c * 8); }
        #pragma unroll
        for (int c = 0; c < 4; ++c)
            #pragma unroll
            for (int k = 0; k < 8; ++k) {
                acc[c * 8 + k] = fmaf(bf2f((unsigned short)va[c][k]), pA, acc[c * 8 + k]);
                acc[c * 8 + k] = fmaf(bf2f((unsigned short)vb[c][k]), pB, acc[c * 8 + k]);
            }
    }

    // reduce ssum over edge slots (keep head bits)
    ssum += __shfl_xor(ssum, 8);
    ssum += __shfl_xor(ssum, 16);
    ssum += __shfl_xor(ssum, 32);
    float inv_s = (ssum > 0.f) ? 1.f / ssum : 0.f;

    // recursive-halving reduce-scatter over eg (static reg indices only)
    int e2 = (lane >> 5) & 1, e1 = (lane >> 4) & 1, e0 = (lane >> 3) & 1;
    float t16[16];
    #pragma unroll
    for (int j = 0; j < 16; ++j) {
        float keep = e2 ? acc[16 + j] : acc[j];
        float send = e2 ? acc[j] : acc[16 + j];
        t16[j] = keep + __shfl_xor(send, 32);
    }
    float t8[8];
    #pragma unroll
    for (int j = 0; j < 8; ++j) {
        float keep = e1 ? t16[8 + j] : t16[j];
        float send = e1 ? t16[j] : t16[8 + j];
        t8[j] = keep + __shfl_xor(send, 16);
    }
    float t4[4];
    #pragma unroll
    for (int j = 0; j < 4; ++j) {
        float keep = e0 ? t8[4 + j] : t8[j];
        float send = e0 ? t8[j] : t8[4 + j];
        t4[j] = keep + __shfl_xor(send, 8);
    }

    int col = fg * 32 + eg * 4;
    float4 bv = *(const float4*)&bias[col];
    float4 o = make_float4(fmaf(t4[0], inv_s, bv.x), fmaf(t4[1], inv_s, bv.y),
                           fmaf(t4[2], inv_s, bv.z), fmaf(t4[3], inv_s, bv.w));
    *(float4*)&out[(size_t)node * HF + col] = o;
}

extern "C" void kernel_launch(void* const* d_in, const int* in_sizes, int n_in,
                              void* d_out, int out_size, void* d_ws, size_t ws_size,
                              hipStream_t stream) {
    const float* feat = (const float*)d_in[0];
    const float* W    = (const float*)d_in[1];
    const float* al   = (const float*)d_in[2];
    const float* ar   = (const float*)d_in[3];
    const float* bias = (const float*)d_in[4];
    const int*   src  = (const int*)d_in[5];
    const int*   dst  = (const int*)d_in[6];
    float* out = (float*)d_out;

    char* ws = (char*)d_ws;
    size_t off = 0;
    unsigned short* h = (unsigned short*)(ws + off); off += (size_t)NN * HF * 2;     // 25.6 MB
    float* el = (float*)(ws + off);                  off += (size_t)NN * NH * 4;
    float* er = (float*)(ws + off);                  off += (size_t)NN * NH * 4;
    int* deg = (int*)(ws + off);                     off += (size_t)DEG_PAD * 4;
    int* row_ptr = (int*)(ws + off);                 off += (size_t)(NN + 1) * 4 + 60;
    off &= ~(size_t)63;
    int* cursor = (int*)(ws + off);                  off += (size_t)NN * 4;
    int* csr_src = (int*)(ws + off);                 off += (size_t)NE * 4;
    unsigned short* Wb_hi = (unsigned short*)(ws + off); off += (size_t)IN_F * HF * 2;

    k0_setup<<<256 + DEG_PAD / 256, 256, 0, stream>>>(W, Wb_hi, deg);
    k1_gemm_deg<<<GEMM_BLOCKS + EDGE_BLOCKS, 256, 0, stream>>>(feat, Wb_hi, h, dst, deg, NN);
    k2_elr_scan<<<12501, 256, 0, stream>>>(h, al, ar, el, er, deg, row_ptr, cursor);
    fill_kernel<<<EDGE_BLOCKS, 256, 0, stream>>>(src, dst, cursor, csr_src);
    agg_kernel<<<12500, 256, 0, stream>>>(h, el, er, row_ptr, csr_src, bias, out);
}